// Round 1
// baseline (5407.329 us; speedup 1.0000x reference)
//
#include <hip/hip_runtime.h>
#include <stdint.h>

#define E_EDGES   500000
#define NMT       3907        // ceil(E/128)
#define EPSV      1e-5f

typedef unsigned short u16;
typedef __attribute__((ext_vector_type(8))) short short8;
typedef __attribute__((ext_vector_type(4))) float f32x4;

__device__ __forceinline__ u16 f2bf(float f) {
  uint32_t u = __float_as_uint(f);
  u += 0x7fffu + ((u >> 16) & 1u);   // RNE
  return (u16)(u >> 16);
}

// ---------------- prep: weights -> bf16 B-fragment layout ----------------
// w1f[((n16*14 + k32)*64 + lane)*8 + j] = bf16(W1[k32*32+(lane>>4)*8+j][n16*16+(lane&15)])
// w2f[((n16*16 + k32)*64 + lane)*8 + j] = bf16(W2[k32*32+(lane>>4)*8+j][n16*16+(lane&15)])
__global__ void prep_weights(const float* __restrict__ W1, const float* __restrict__ W2,
                             u16* __restrict__ w1f, u16* __restrict__ w2f) {
  int idx = blockIdx.x * blockDim.x + threadIdx.x;
  if (idx < 32*14*64) {
    int lane = idx & 63; int t = idx >> 6; int k32 = t % 14; int n16 = t / 14;
    int n = n16*16 + (lane & 15); int k0 = k32*32 + (lane >> 4)*8;
    short8 pk;
#pragma unroll
    for (int j = 0; j < 8; ++j) pk[j] = (short)f2bf(W1[(size_t)(k0 + j)*512 + n]);
    *(short8*)&w1f[(size_t)idx * 8] = pk;
  } else if (idx < 32*14*64 + 8*16*64) {
    int i2 = idx - 32*14*64;
    int lane = i2 & 63; int t = i2 >> 6; int k32 = t % 16; int n16 = t / 16;
    int n = n16*16 + (lane & 15); int k0 = k32*32 + (lane >> 4)*8;
    short8 pk;
#pragma unroll
    for (int j = 0; j < 8; ++j) pk[j] = (short)f2bf(W2[(size_t)(k0 + j)*128 + n]);
    *(short8*)&w2f[(size_t)i2 * 8] = pk;
  }
}

__global__ void count_kernel(const int* __restrict__ batch, float* __restrict__ cnt) {
  int i = blockIdx.x * blockDim.x + threadIdx.x;
  int stride = gridDim.x * blockDim.x;
  for (; i < E_EDGES; i += stride) atomicAdd(&cnt[batch[i]], 1.0f);
}

// ---------------- GEMM1: X[E,448] @ W1 -> relu -> H (A-frag layout, bf16) ----------------
// X = concat(src,dest,edge,u[batch]) built on the fly during staging.
__global__ __launch_bounds__(256)
void gemm1_kernel(const float* __restrict__ srcp, const float* __restrict__ destp,
                  const float* __restrict__ edgep, const float* __restrict__ up,
                  const int* __restrict__ batch, const float* __restrict__ b1,
                  const u16* __restrict__ w1f, u16* __restrict__ hfrag,
                  int mtile0, int nblocks) {
  // bijective XCD remap (m204): same-mtile quads contiguous on one XCD
  int orig = blockIdx.x;
  int q = nblocks >> 3, r = nblocks & 7;
  int xcd = orig & 7;
  int nb = (xcd < r ? xcd*(q+1) : r*(q+1) + (xcd - r)*q) + (orig >> 3);
  int mt = nb >> 2, nt = nb & 3;

  const int tid  = threadIdx.x;
  const int lane = tid & 63;
  const int wave = tid >> 6;
  const int wr = wave >> 1, wc = wave & 1;
  const int l15 = lane & 15, l4 = lane >> 4;

  __shared__ __align__(16) u16 lds[128*136];   // staging [128][72]; epilogue [128][136]

  long grow0 = (long)(mtile0 + mt) * 128;

  f32x4 acc[4][4];
#pragma unroll
  for (int mi = 0; mi < 4; ++mi)
#pragma unroll
    for (int nj = 0; nj < 4; ++nj) {
      float bv = b1[nt*128 + wc*64 + nj*16 + l15];
      acc[mi][nj] = (f32x4){bv, bv, bv, bv};
    }

  const int srow = tid >> 1;
  const int skh  = (tid & 1) * 32;
  long sgrow = grow0 + srow;

#pragma unroll 1
  for (int kt = 0; kt < 7; ++kt) {
    // ---- stage A: 128 rows x 64 k of f32 -> bf16 -> LDS [128][72]
    int kbase = kt*64 + skh;
    float v[32];
    if (sgrow < E_EDGES) {
      const float* sp;
      if (kbase < 128)      sp = srcp  + sgrow*128 + kbase;
      else if (kbase < 256) sp = destp + sgrow*128 + (kbase - 128);
      else if (kbase < 384) sp = edgep + sgrow*128 + (kbase - 256);
      else                  sp = up + (size_t)batch[sgrow]*64 + (kbase - 384);
#pragma unroll
      for (int c = 0; c < 8; ++c) {
        f32x4 t = *(const f32x4*)(sp + c*4);
        v[c*4+0]=t[0]; v[c*4+1]=t[1]; v[c*4+2]=t[2]; v[c*4+3]=t[3];
      }
    } else {
#pragma unroll
      for (int c = 0; c < 32; ++c) v[c] = 0.f;
    }
#pragma unroll
    for (int c = 0; c < 4; ++c) {
      short8 pk;
#pragma unroll
      for (int j = 0; j < 8; ++j) pk[j] = (short)f2bf(v[c*8+j]);
      *(short8*)&lds[srow*72 + skh + c*8] = pk;
    }
    __syncthreads();
    // ---- MFMA: A-frags from LDS, B-frags direct from global (L2-resident)
#pragma unroll
    for (int kk = 0; kk < 2; ++kk) {
      short8 a[4], b[4];
      int k32g = kt*2 + kk;
#pragma unroll
      for (int mi = 0; mi < 4; ++mi)
        a[mi] = *(const short8*)&lds[(wr*64 + mi*16 + l15)*72 + kk*32 + l4*8];
#pragma unroll
      for (int nj = 0; nj < 4; ++nj) {
        int n16 = nt*8 + wc*4 + nj;
        b[nj] = *(const short8*)&w1f[((size_t)(n16*14 + k32g)*64 + lane)*8];
      }
#pragma unroll
      for (int mi = 0; mi < 4; ++mi)
#pragma unroll
        for (int nj = 0; nj < 4; ++nj)
          acc[mi][nj] = __builtin_amdgcn_mfma_f32_16x16x32_bf16(a[mi], b[nj], acc[mi][nj], 0, 0, 0);
    }
    __syncthreads();
  }

  // ---- epilogue: relu -> bf16 -> LDS bounce [128][136] -> H in A-frag layout
#pragma unroll
  for (int mi = 0; mi < 4; ++mi)
#pragma unroll
    for (int nj = 0; nj < 4; ++nj) {
      int lcol = wc*64 + nj*16 + l15;
#pragma unroll
      for (int rr = 0; rr < 4; ++rr) {
        int lrow = wr*64 + mi*16 + l4*4 + rr;
        lds[lrow*136 + lcol] = f2bf(fmaxf(acc[mi][nj][rr], 0.f));
      }
    }
  __syncthreads();
#pragma unroll
  for (int f = 0; f < 8; ++f) {
    int fi = wave*8 + f;
    int k32loc = fi >> 3, m16 = fi & 7;
    short8 hv = *(const short8*)&lds[(m16*16 + l15)*136 + k32loc*32 + l4*8];
    size_t off = ((((size_t)mt*16 + (nt*4 + k32loc))*8 + m16)*64 + lane)*8;
    *(short8*)&hfrag[off] = hv;
  }
}

// ---------------- GEMM2: H[E,512] @ W2 + b2 + edge -> Y (f32, into d_out). No LDS. ----------------
__global__ __launch_bounds__(256)
void gemm2_kernel(const u16* __restrict__ hfrag, const u16* __restrict__ w2f,
                  const float* __restrict__ b2, const float* __restrict__ edgep,
                  float* __restrict__ outp, int mtile0) {
  int mt = blockIdx.x;
  const int tid = threadIdx.x;
  const int lane = tid & 63, wave = tid >> 6;
  const int wr = wave >> 1, wc = wave & 1;
  const int l15 = lane & 15, l4 = lane >> 4;

  f32x4 acc[4][4];
#pragma unroll
  for (int mi = 0; mi < 4; ++mi)
#pragma unroll
    for (int nj = 0; nj < 4; ++nj) {
      float bv = b2[wc*64 + nj*16 + l15];
      acc[mi][nj] = (f32x4){bv, bv, bv, bv};
    }

#pragma unroll 2
  for (int k32 = 0; k32 < 16; ++k32) {
    short8 a[4], b[4];
#pragma unroll
    for (int mi = 0; mi < 4; ++mi) {
      int m16 = wr*4 + mi;
      a[mi] = *(const short8*)&hfrag[((((size_t)mt*16 + k32)*8 + m16)*64 + lane)*8];
    }
#pragma unroll
    for (int nj = 0; nj < 4; ++nj) {
      int n16 = wc*4 + nj;
      b[nj] = *(const short8*)&w2f[(((size_t)(n16*16 + k32))*64 + lane)*8];
    }
#pragma unroll
    for (int mi = 0; mi < 4; ++mi)
#pragma unroll
      for (int nj = 0; nj < 4; ++nj)
        acc[mi][nj] = __builtin_amdgcn_mfma_f32_16x16x32_bf16(a[mi], b[nj], acc[mi][nj], 0, 0, 0);
  }

  long grow0 = (long)(mtile0 + mt) * 128;
#pragma unroll
  for (int mi = 0; mi < 4; ++mi)
#pragma unroll
    for (int rr = 0; rr < 4; ++rr) {
      long grow = grow0 + wr*64 + mi*16 + l4*4 + rr;
      if (grow < E_EDGES) {
#pragma unroll
        for (int nj = 0; nj < 4; ++nj) {
          int col = wc*64 + nj*16 + l15;
          size_t gi = (size_t)grow*128 + col;
          outp[gi] = acc[mi][nj][rr] + edgep[gi];
        }
      }
    }
}

// ---------------- stats: per-graph sum & sumsq of Y (batch sorted -> run accumulation) ----------------
__global__ void stats_kernel(const float* __restrict__ y, const int* __restrict__ batch,
                             float* __restrict__ gsum, float* __restrict__ gsum2) {
  const int col = threadIdx.x & 127;
  const int rp  = threadIdx.x >> 7;
  long r0 = (long)blockIdx.x * 1024;
  long rend = r0 + 1024; if (rend > E_EDGES) rend = E_EDGES;
  float s = 0.f, s2 = 0.f; int gcur = -1;
  for (long rr = r0 + rp; rr < rend; rr += 2) {
    int g = batch[rr];
    if (g != gcur) {
      if (gcur >= 0) { atomicAdd(&gsum[gcur*128+col], s); atomicAdd(&gsum2[gcur*128+col], s2); }
      gcur = g; s = 0.f; s2 = 0.f;
    }
    float v = y[rr*128 + col];
    s += v; s2 += v*v;
  }
  if (gcur >= 0) { atomicAdd(&gsum[gcur*128+col], s); atomicAdd(&gsum2[gcur*128+col], s2); }
}

// ---------------- finalize: scale/shift per (graph, dim) ----------------
__global__ void finalize_kernel(const float* __restrict__ gsum, const float* __restrict__ gsum2,
                                const float* __restrict__ cnt,
                                const float* __restrict__ gnw, const float* __restrict__ gnb,
                                const float* __restrict__ ms,
                                float* __restrict__ scale, float* __restrict__ shift) {
  int idx = blockIdx.x*blockDim.x + threadIdx.x;
  if (idx >= 64*128) return;
  int g = idx >> 7, d = idx & 127;
  float c = fmaxf(cnt[g], 1.0f);
  float mean = gsum[idx] / c;
  float mm = mean * ms[d];
  // E[(x-mm)^2] = E[x^2] - 2*mm*E[x] + mm^2
  float var = gsum2[idx] / c - 2.f*mm*mean + mm*mm;
  float sc = gnw[d] / sqrtf(var + EPSV);
  scale[idx] = sc;
  shift[idx] = gnb[d] - mm*sc;
}

// ---------------- norm: in-place y = y*scale[g] + shift[g] ----------------
__global__ void norm_kernel(float* __restrict__ y, const int* __restrict__ batch,
                            const float* __restrict__ scale, const float* __restrict__ shift) {
  long i = (long)blockIdx.x*blockDim.x + threadIdx.x;
  const long n4 = (long)E_EDGES * 32;
  long stride = (long)gridDim.x*blockDim.x;
  for (; i < n4; i += stride) {
    long row = i >> 5;
    int dq = (int)(i & 31) << 2;
    int g = batch[row];
    f32x4 v = *(f32x4*)(y + i*4);
    f32x4 sc = *(const f32x4*)(scale + g*128 + dq);
    f32x4 sh = *(const f32x4*)(shift + g*128 + dq);
    v = v*sc + sh;
    *(f32x4*)(y + i*4) = v;
  }
}

extern "C" void kernel_launch(void* const* d_in, const int* in_sizes, int n_in,
                              void* d_out, int out_size, void* d_ws, size_t ws_size,
                              hipStream_t stream) {
  const float* srcp  = (const float*)d_in[0];
  const float* destp = (const float*)d_in[1];
  const float* edgep = (const float*)d_in[2];
  const float* up    = (const float*)d_in[3];
  const int*   batch = (const int*)d_in[4];
  const float* W1    = (const float*)d_in[5];
  const float* b1    = (const float*)d_in[6];
  const float* W2    = (const float*)d_in[7];
  const float* b2    = (const float*)d_in[8];
  const float* gnw   = (const float*)d_in[9];
  const float* gnb   = (const float*)d_in[10];
  const float* ms    = (const float*)d_in[11];
  float* outp = (float*)d_out;

  char* ws = (char*)d_ws;
  u16*   w1f   = (u16*)(ws + 0);          // 458752 B
  u16*   w2f   = (u16*)(ws + 458752);     // 131072 B
  float* gsum  = (float*)(ws + 589824);   // 32768 B
  float* gsum2 = (float*)(ws + 622592);   // 32768 B
  float* cntp  = (float*)(ws + 655360);   // 1024 B
  float* scale = (float*)(ws + 656384);   // 32768 B
  float* shift = (float*)(ws + 689152);   // 32768 B
  u16*   hbuf  = (u16*)(ws + 1048576);    // H-frag chunks: 131072 B per mtile

  hipMemsetAsync(ws + 589824, 0, 66560, stream);  // gsum, gsum2, cnt
  prep_weights<<<dim3(144), dim3(256), 0, stream>>>(W1, W2, w1f, w2f);
  count_kernel<<<dim3(489), dim3(256), 0, stream>>>(batch, cntp);

  size_t avail = ws_size > 1048576 ? ws_size - 1048576 : 0;
  long chunkM = (long)(avail / 131072);
  if (chunkM < 1) chunkM = 1;
  if (chunkM > NMT) chunkM = NMT;

  for (int m0 = 0; m0 < NMT; m0 += (int)chunkM) {
    int cm = (NMT - m0 < (int)chunkM) ? (NMT - m0) : (int)chunkM;
    gemm1_kernel<<<dim3(cm*4), dim3(256), 0, stream>>>(srcp, destp, edgep, up, batch, b1,
                                                       w1f, hbuf, m0, cm*4);
    gemm2_kernel<<<dim3(cm), dim3(256), 0, stream>>>(hbuf, w2f, b2, edgep, outp, m0);
  }

  stats_kernel<<<dim3(489), dim3(256), 0, stream>>>(outp, batch, gsum, gsum2);
  finalize_kernel<<<dim3(32), dim3(256), 0, stream>>>(gsum, gsum2, cntp, gnw, gnb, ms, scale, shift);
  norm_kernel<<<dim3(2048), dim3(256), 0, stream>>>(outp, batch, scale, shift);
}

// Round 2
// 1294.464 us; speedup vs baseline: 4.1773x; 4.1773x over previous
//
#include <hip/hip_runtime.h>
#include <stdint.h>

#define E_EDGES   500000
#define NMT       3907        // ceil(E/128)
#define EPSV      1e-5f

typedef unsigned short u16;
typedef __attribute__((ext_vector_type(8))) short short8;
typedef __attribute__((ext_vector_type(4))) float f32x4;

__device__ __forceinline__ u16 f2bf(float f) {
  uint32_t u = __float_as_uint(f);
  u += 0x7fffu + ((u >> 16) & 1u);   // RNE
  return (u16)(u >> 16);
}

// ---------------- prep: weights -> bf16 B-fragment layout ----------------
__global__ void prep_weights(const float* __restrict__ W1, const float* __restrict__ W2,
                             u16* __restrict__ w1f, u16* __restrict__ w2f) {
  int idx = blockIdx.x * blockDim.x + threadIdx.x;
  if (idx < 32*14*64) {
    int lane = idx & 63; int t = idx >> 6; int k32 = t % 14; int n16 = t / 14;
    int n = n16*16 + (lane & 15); int k0 = k32*32 + (lane >> 4)*8;
    short8 pk;
#pragma unroll
    for (int j = 0; j < 8; ++j) pk[j] = (short)f2bf(W1[(size_t)(k0 + j)*512 + n]);
    *(short8*)&w1f[(size_t)idx * 8] = pk;
  } else if (idx < 32*14*64 + 8*16*64) {
    int i2 = idx - 32*14*64;
    int lane = i2 & 63; int t = i2 >> 6; int k32 = t % 16; int n16 = t / 16;
    int n = n16*16 + (lane & 15); int k0 = k32*32 + (lane >> 4)*8;
    short8 pk;
#pragma unroll
    for (int j = 0; j < 8; ++j) pk[j] = (short)f2bf(W2[(size_t)(k0 + j)*128 + n]);
    *(short8*)&w2f[(size_t)i2 * 8] = pk;
  }
}

// ---------------- GEMM1: X[E,448] @ W1 -> relu -> H (A-frag layout, bf16) ----------------
__global__ __launch_bounds__(256)
void gemm1_kernel(const float* __restrict__ srcp, const float* __restrict__ destp,
                  const float* __restrict__ edgep, const float* __restrict__ up,
                  const int* __restrict__ batch, const float* __restrict__ b1,
                  const u16* __restrict__ w1f, u16* __restrict__ hfrag,
                  int mtile0, int nblocks) {
  // bijective XCD remap (m204): same-mtile quads contiguous on one XCD
  int orig = blockIdx.x;
  int q = nblocks >> 3, r = nblocks & 7;
  int xcd = orig & 7;
  int nb = (xcd < r ? xcd*(q+1) : r*(q+1) + (xcd - r)*q) + (orig >> 3);
  int mt = nb >> 2, nt = nb & 3;

  const int tid  = threadIdx.x;
  const int lane = tid & 63;
  const int wave = tid >> 6;
  const int wr = wave >> 1, wc = wave & 1;
  const int l15 = lane & 15, l4 = lane >> 4;

  __shared__ __align__(16) u16 lds[128*136];   // staging [128][72]; epilogue [128][136]

  long grow0 = (long)(mtile0 + mt) * 128;

  f32x4 acc[4][4];
#pragma unroll
  for (int mi = 0; mi < 4; ++mi)
#pragma unroll
    for (int nj = 0; nj < 4; ++nj) {
      float bv = b1[nt*128 + wc*64 + nj*16 + l15];
      acc[mi][nj] = (f32x4){bv, bv, bv, bv};
    }

  const int srow = tid >> 1;
  const int skh  = (tid & 1) * 32;
  long sgrow = grow0 + srow;

#pragma unroll 1
  for (int kt = 0; kt < 7; ++kt) {
    // ---- stage A: 128 rows x 64 k of f32 -> bf16 -> LDS [128][72]
    int kbase = kt*64 + skh;
    float v[32];
    if (sgrow < E_EDGES) {
      const float* sp;
      if (kbase < 128)      sp = srcp  + sgrow*128 + kbase;
      else if (kbase < 256) sp = destp + sgrow*128 + (kbase - 128);
      else if (kbase < 384) sp = edgep + sgrow*128 + (kbase - 256);
      else                  sp = up + (size_t)batch[sgrow]*64 + (kbase - 384);
#pragma unroll
      for (int c = 0; c < 8; ++c) {
        f32x4 t = *(const f32x4*)(sp + c*4);
        v[c*4+0]=t[0]; v[c*4+1]=t[1]; v[c*4+2]=t[2]; v[c*4+3]=t[3];
      }
    } else {
#pragma unroll
      for (int c = 0; c < 32; ++c) v[c] = 0.f;
    }
#pragma unroll
    for (int c = 0; c < 4; ++c) {
      short8 pk;
#pragma unroll
      for (int j = 0; j < 8; ++j) pk[j] = (short)f2bf(v[c*8+j]);
      *(short8*)&lds[srow*72 + skh + c*8] = pk;
    }
    __syncthreads();
    // ---- MFMA: A-frags from LDS, B-frags direct from global (L2-resident)
#pragma unroll
    for (int kk = 0; kk < 2; ++kk) {
      short8 a[4], b[4];
      int k32g = kt*2 + kk;
#pragma unroll
      for (int mi = 0; mi < 4; ++mi)
        a[mi] = *(const short8*)&lds[(wr*64 + mi*16 + l15)*72 + kk*32 + l4*8];
#pragma unroll
      for (int nj = 0; nj < 4; ++nj) {
        int n16 = nt*8 + wc*4 + nj;
        b[nj] = *(const short8*)&w1f[((size_t)(n16*14 + k32g)*64 + lane)*8];
      }
#pragma unroll
      for (int mi = 0; mi < 4; ++mi)
#pragma unroll
        for (int nj = 0; nj < 4; ++nj)
          acc[mi][nj] = __builtin_amdgcn_mfma_f32_16x16x32_bf16(a[mi], b[nj], acc[mi][nj], 0, 0, 0);
    }
    __syncthreads();
  }

  // ---- epilogue: relu -> bf16 -> LDS bounce [128][136] -> H in A-frag layout
#pragma unroll
  for (int mi = 0; mi < 4; ++mi)
#pragma unroll
    for (int nj = 0; nj < 4; ++nj) {
      int lcol = wc*64 + nj*16 + l15;
#pragma unroll
      for (int rr = 0; rr < 4; ++rr) {
        int lrow = wr*64 + mi*16 + l4*4 + rr;
        lds[lrow*136 + lcol] = f2bf(fmaxf(acc[mi][nj][rr], 0.f));
      }
    }
  __syncthreads();
#pragma unroll
  for (int f = 0; f < 8; ++f) {
    int fi = wave*8 + f;
    int k32loc = fi >> 3, m16 = fi & 7;
    short8 hv = *(const short8*)&lds[(m16*16 + l15)*136 + k32loc*32 + l4*8];
    size_t off = ((((size_t)mt*16 + (nt*4 + k32loc))*8 + m16)*64 + lane)*8;
    *(short8*)&hfrag[off] = hv;
  }
}

// ---------------- GEMM2: H[E,512] @ W2 + b2 + edge -> Y (f32, into d_out). No LDS. ----------------
__global__ __launch_bounds__(256)
void gemm2_kernel(const u16* __restrict__ hfrag, const u16* __restrict__ w2f,
                  const float* __restrict__ b2, const float* __restrict__ edgep,
                  float* __restrict__ outp, int mtile0) {
  int mt = blockIdx.x;
  const int tid = threadIdx.x;
  const int lane = tid & 63, wave = tid >> 6;
  const int wr = wave >> 1, wc = wave & 1;
  const int l15 = lane & 15, l4 = lane >> 4;

  f32x4 acc[4][4];
#pragma unroll
  for (int mi = 0; mi < 4; ++mi)
#pragma unroll
    for (int nj = 0; nj < 4; ++nj) {
      float bv = b2[wc*64 + nj*16 + l15];
      acc[mi][nj] = (f32x4){bv, bv, bv, bv};
    }

#pragma unroll 2
  for (int k32 = 0; k32 < 16; ++k32) {
    short8 a[4], b[4];
#pragma unroll
    for (int mi = 0; mi < 4; ++mi) {
      int m16 = wr*4 + mi;
      a[mi] = *(const short8*)&hfrag[((((size_t)mt*16 + k32)*8 + m16)*64 + lane)*8];
    }
#pragma unroll
    for (int nj = 0; nj < 4; ++nj) {
      int n16 = wc*4 + nj;
      b[nj] = *(const short8*)&w2f[(((size_t)(n16*16 + k32))*64 + lane)*8];
    }
#pragma unroll
    for (int mi = 0; mi < 4; ++mi)
#pragma unroll
      for (int nj = 0; nj < 4; ++nj)
        acc[mi][nj] = __builtin_amdgcn_mfma_f32_16x16x32_bf16(a[mi], b[nj], acc[mi][nj], 0, 0, 0);
  }

  long grow0 = (long)(mtile0 + mt) * 128;
#pragma unroll
  for (int mi = 0; mi < 4; ++mi)
#pragma unroll
    for (int rr = 0; rr < 4; ++rr) {
      long grow = grow0 + wr*64 + mi*16 + l4*4 + rr;
      if (grow < E_EDGES) {
#pragma unroll
        for (int nj = 0; nj < 4; ++nj) {
          int col = wc*64 + nj*16 + l15;
          size_t gi = (size_t)grow*128 + col;
          outp[gi] = acc[mi][nj][rr] + edgep[gi];
        }
      }
    }
}

// ---------------- stats: per-graph count, sum, sumsq of Y (batch sorted -> run accumulation) ----------------
__global__ void stats_kernel(const float* __restrict__ y, const int* __restrict__ batch,
                             float* __restrict__ gsum, float* __restrict__ gsum2,
                             float* __restrict__ gcnt) {
  const int col = threadIdx.x & 127;
  const int rp  = threadIdx.x >> 7;
  long r0 = (long)blockIdx.x * 1024;
  long rend = r0 + 1024; if (rend > E_EDGES) rend = E_EDGES;
  float s = 0.f, s2 = 0.f, sc = 0.f; int gcur = -1;
  for (long rr = r0 + rp; rr < rend; rr += 2) {
    int g = batch[rr];
    if (g != gcur) {
      if (gcur >= 0) {
        atomicAdd(&gsum[gcur*128+col], s); atomicAdd(&gsum2[gcur*128+col], s2);
        if (col == 0) atomicAdd(&gcnt[gcur], sc);
      }
      gcur = g; s = 0.f; s2 = 0.f; sc = 0.f;
    }
    float v = y[rr*128 + col];
    s += v; s2 += v*v; sc += 1.f;
  }
  if (gcur >= 0) {
    atomicAdd(&gsum[gcur*128+col], s); atomicAdd(&gsum2[gcur*128+col], s2);
    if (col == 0) atomicAdd(&gcnt[gcur], sc);
  }
}

// ---------------- finalize: scale/shift per (graph, dim) ----------------
__global__ void finalize_kernel(const float* __restrict__ gsum, const float* __restrict__ gsum2,
                                const float* __restrict__ cnt,
                                const float* __restrict__ gnw, const float* __restrict__ gnb,
                                const float* __restrict__ ms,
                                float* __restrict__ scale, float* __restrict__ shift) {
  int idx = blockIdx.x*blockDim.x + threadIdx.x;
  if (idx >= 64*128) return;
  int g = idx >> 7, d = idx & 127;
  float c = fmaxf(cnt[g], 1.0f);
  float mean = gsum[idx] / c;
  float mm = mean * ms[d];
  // E[(x-mm)^2] = E[x^2] - 2*mm*E[x] + mm^2
  float var = gsum2[idx] / c - 2.f*mm*mean + mm*mm;
  float sc = gnw[d] / sqrtf(var + EPSV);
  scale[idx] = sc;
  shift[idx] = gnb[d] - mm*sc;
}

// ---------------- norm: in-place y = y*scale[g] + shift[g] ----------------
__global__ void norm_kernel(float* __restrict__ y, const int* __restrict__ batch,
                            const float* __restrict__ scale, const float* __restrict__ shift) {
  long i = (long)blockIdx.x*blockDim.x + threadIdx.x;
  const long n4 = (long)E_EDGES * 32;
  long stride = (long)gridDim.x*blockDim.x;
  for (; i < n4; i += stride) {
    long row = i >> 5;
    int dq = (int)(i & 31) << 2;
    int g = batch[row];
    f32x4 v = *(f32x4*)(y + i*4);
    f32x4 sc = *(const f32x4*)(scale + g*128 + dq);
    f32x4 sh = *(const f32x4*)(shift + g*128 + dq);
    v = v*sc + sh;
    *(f32x4*)(y + i*4) = v;
  }
}

extern "C" void kernel_launch(void* const* d_in, const int* in_sizes, int n_in,
                              void* d_out, int out_size, void* d_ws, size_t ws_size,
                              hipStream_t stream) {
  const float* srcp  = (const float*)d_in[0];
  const float* destp = (const float*)d_in[1];
  const float* edgep = (const float*)d_in[2];
  const float* up    = (const float*)d_in[3];
  const int*   batch = (const int*)d_in[4];
  const float* W1    = (const float*)d_in[5];
  const float* b1    = (const float*)d_in[6];
  const float* W2    = (const float*)d_in[7];
  const float* b2    = (const float*)d_in[8];
  const float* gnw   = (const float*)d_in[9];
  const float* gnb   = (const float*)d_in[10];
  const float* ms    = (const float*)d_in[11];
  float* outp = (float*)d_out;

  char* ws = (char*)d_ws;
  u16*   w1f   = (u16*)(ws + 0);          // 458752 B
  u16*   w2f   = (u16*)(ws + 458752);     // 131072 B
  float* gsum  = (float*)(ws + 589824);   // 32768 B
  float* gsum2 = (float*)(ws + 622592);   // 32768 B
  float* cntp  = (float*)(ws + 655360);   // 1024 B
  float* scale = (float*)(ws + 656384);   // 32768 B
  float* shift = (float*)(ws + 689152);   // 32768 B
  u16*   hbuf  = (u16*)(ws + 1048576);    // H-frag chunks: 131072 B per mtile

  hipMemsetAsync(ws + 589824, 0, 66560, stream);  // gsum, gsum2, cnt
  prep_weights<<<dim3(144), dim3(256), 0, stream>>>(W1, W2, w1f, w2f);

  size_t avail = ws_size > 1048576 ? ws_size - 1048576 : 0;
  long chunkM = (long)(avail / 131072);
  if (chunkM < 1) chunkM = 1;
  if (chunkM > NMT) chunkM = NMT;

  for (int m0 = 0; m0 < NMT; m0 += (int)chunkM) {
    int cm = (NMT - m0 < (int)chunkM) ? (NMT - m0) : (int)chunkM;
    gemm1_kernel<<<dim3(cm*4), dim3(256), 0, stream>>>(srcp, destp, edgep, up, batch, b1,
                                                       w1f, hbuf, m0, cm*4);
    gemm2_kernel<<<dim3(cm), dim3(256), 0, stream>>>(hbuf, w2f, b2, edgep, outp, m0);
  }

  stats_kernel<<<dim3(489), dim3(256), 0, stream>>>(outp, batch, gsum, gsum2, cntp);
  finalize_kernel<<<dim3(32), dim3(256), 0, stream>>>(gsum, gsum2, cntp, gnw, gnb, ms, scale, shift);
  norm_kernel<<<dim3(2048), dim3(256), 0, stream>>>(outp, batch, scale, shift);
}

// Round 3
// 914.865 us; speedup vs baseline: 5.9105x; 1.4149x over previous
//
#include <hip/hip_runtime.h>
#include <stdint.h>

#define E_EDGES   500000
#define NBLK      7813        // ceil(E/64)
#define EPSV      1e-5f

typedef unsigned short u16;
typedef __attribute__((ext_vector_type(8))) short short8;
typedef __attribute__((ext_vector_type(4))) float f32x4;

__device__ __forceinline__ u16 f2bf(float f) {
  uint32_t u = __float_as_uint(f);
  u += 0x7fffu + ((u >> 16) & 1u);   // RNE
  return (u16)(u >> 16);
}

// ---------------- prep: weights -> bf16 B-fragment layout ----------------
// w1f[((n16*14 + k32)*64 + lane)*8 + j] = bf16(W1[k32*32+(lane>>4)*8+j][n16*16+(lane&15)])
// w2f[((n16*16 + k32)*64 + lane)*8 + j] = bf16(W2[k32*32+(lane>>4)*8+j][n16*16+(lane&15)])
__global__ void prep_weights(const float* __restrict__ W1, const float* __restrict__ W2,
                             u16* __restrict__ w1f, u16* __restrict__ w2f) {
  int idx = blockIdx.x * blockDim.x + threadIdx.x;
  if (idx < 32*14*64) {
    int lane = idx & 63; int t = idx >> 6; int k32 = t % 14; int n16 = t / 14;
    int n = n16*16 + (lane & 15); int k0 = k32*32 + (lane >> 4)*8;
    short8 pk;
#pragma unroll
    for (int j = 0; j < 8; ++j) pk[j] = (short)f2bf(W1[(size_t)(k0 + j)*512 + n]);
    *(short8*)&w1f[(size_t)idx * 8] = pk;
  } else if (idx < 32*14*64 + 8*16*64) {
    int i2 = idx - 32*14*64;
    int lane = i2 & 63; int t = i2 >> 6; int k32 = t % 16; int n16 = t / 16;
    int n = n16*16 + (lane & 15); int k0 = k32*32 + (lane >> 4)*8;
    short8 pk;
#pragma unroll
    for (int j = 0; j < 8; ++j) pk[j] = (short)f2bf(W2[(size_t)(k0 + j)*128 + n]);
    *(short8*)&w2f[(size_t)i2 * 8] = pk;
  }
}

// ---------------- fused: Y = relu(X@W1+b1)@W2 + b2 + edge ----------------
// Block: 64 edges x full pipeline. 8 waves; wave w owns hidden-cols [w*64, w*64+64).
// LDS: union{ stage X-tile [64][64] bf16 (8KB), H [64][512] bf16 (64KB) }, XOR-swizzled.
#define SWZ16(row, byte) ((byte) ^ (((row) & 7) << 4))

__global__ __launch_bounds__(512, 4)
void fused_kernel(const float* __restrict__ srcp, const float* __restrict__ destp,
                  const float* __restrict__ edgep, const float* __restrict__ up,
                  const int* __restrict__ batch, const float* __restrict__ b1,
                  const float* __restrict__ b2,
                  const u16* __restrict__ w1f, const u16* __restrict__ w2f,
                  float* __restrict__ outp) {
  const int tid  = threadIdx.x;
  const int lane = tid & 63;
  const int w    = tid >> 6;         // wave 0..7
  const int l15  = lane & 15, l4 = lane >> 4;

  __shared__ __align__(16) u16 lds[64*512];   // 64 KB
  char* ldsb = (char*)lds;

  const long grow0 = (long)blockIdx.x * 64;

  // acc1[mi][nj]: GEMM1 C-frags, rows = edges (mi*16 + l4*4 + reg), cols = w*64 + nj*16 + l15
  f32x4 acc1[4][4];
#pragma unroll
  for (int mi = 0; mi < 4; ++mi)
#pragma unroll
    for (int nj = 0; nj < 4; ++nj) {
      float bv = b1[w*64 + nj*16 + l15];
      acc1[mi][nj] = (f32x4){bv, bv, bv, bv};
    }

  const int srow = tid >> 3;          // 0..63
  const int koff = (tid & 7) * 8;     // 0..56
  const long sgrow = grow0 + srow;
  const int sbyte = srow*128 + SWZ16(srow, koff*2);

#pragma unroll
  for (int kt = 0; kt < 7; ++kt) {
    // ---- stage: 64 rows x 64 k of X (f32 -> bf16), swizzled into lds[0..8K)
    float v[8];
    if (sgrow < E_EDGES) {
      const float* sp;
      if (kt == 0)      sp = srcp  + sgrow*128 + koff;
      else if (kt == 1) sp = srcp  + sgrow*128 + 64 + koff;
      else if (kt == 2) sp = destp + sgrow*128 + koff;
      else if (kt == 3) sp = destp + sgrow*128 + 64 + koff;
      else if (kt == 4) sp = edgep + sgrow*128 + koff;
      else if (kt == 5) sp = edgep + sgrow*128 + 64 + koff;
      else              sp = up + (size_t)batch[sgrow]*64 + koff;
      f32x4 t0 = *(const f32x4*)(sp);
      f32x4 t1 = *(const f32x4*)(sp + 4);
      v[0]=t0[0]; v[1]=t0[1]; v[2]=t0[2]; v[3]=t0[3];
      v[4]=t1[0]; v[5]=t1[1]; v[6]=t1[2]; v[7]=t1[3];
    } else {
#pragma unroll
      for (int c = 0; c < 8; ++c) v[c] = 0.f;
    }
    short8 pk;
#pragma unroll
    for (int j = 0; j < 8; ++j) pk[j] = (short)f2bf(v[j]);
    *(short8*)(ldsb + sbyte) = pk;
    __syncthreads();

    // ---- MFMA: A from LDS (swizzled), B (w1f) direct from global (L2-resident)
#pragma unroll
    for (int kk = 0; kk < 2; ++kk) {
      int k32 = kt*2 + kk;
      short8 a[4], b[4];
#pragma unroll
      for (int mi = 0; mi < 4; ++mi) {
        int row = mi*16 + l15;
        a[mi] = *(const short8*)(ldsb + row*128 + SWZ16(row, kk*64 + l4*16));
      }
#pragma unroll
      for (int nj = 0; nj < 4; ++nj) {
        int n16 = w*4 + nj;
        b[nj] = *(const short8*)&w1f[((size_t)(n16*14 + k32)*64 + lane)*8];
      }
#pragma unroll
      for (int mi = 0; mi < 4; ++mi)
#pragma unroll
        for (int nj = 0; nj < 4; ++nj)
          acc1[mi][nj] = __builtin_amdgcn_mfma_f32_16x16x32_bf16(a[mi], b[nj], acc1[mi][nj], 0, 0, 0);
    }
    __syncthreads();
  }

  // ---- epilogue 1: relu -> bf16 -> H in LDS [64][512] (row-major, swizzled)
#pragma unroll
  for (int nj = 0; nj < 4; ++nj) {
    int n = w*64 + nj*16 + l15;
#pragma unroll
    for (int mi = 0; mi < 4; ++mi)
#pragma unroll
      for (int rr = 0; rr < 4; ++rr) {
        int row = mi*16 + l4*4 + rr;
        *(u16*)(ldsb + row*1024 + SWZ16(row, n*2)) = f2bf(fmaxf(acc1[mi][nj][rr], 0.f));
      }
  }
  __syncthreads();

  // ---- GEMM2: Y[64][128] = H @ W2 + b2 + edge. Wave w owns out-cols [w*16, w*16+16).
  const int col = w*16 + l15;
  float bv2 = b2[col];
  f32x4 acc2[4];
#pragma unroll
  for (int mi = 0; mi < 4; ++mi) acc2[mi] = (f32x4){bv2, bv2, bv2, bv2};

#pragma unroll
  for (int kb = 0; kb < 16; ++kb) {
    short8 bfrag = *(const short8*)&w2f[((size_t)(w*16 + kb)*64 + lane)*8];
#pragma unroll
    for (int mi = 0; mi < 4; ++mi) {
      int row = mi*16 + l15;
      short8 a = *(const short8*)(ldsb + row*1024 + SWZ16(row, kb*64 + l4*16));
      acc2[mi] = __builtin_amdgcn_mfma_f32_16x16x32_bf16(a, bfrag, acc2[mi], 0, 0, 0);
    }
  }

  // ---- epilogue 2: + edge_attr, store f32
#pragma unroll
  for (int mi = 0; mi < 4; ++mi)
#pragma unroll
    for (int rr = 0; rr < 4; ++rr) {
      long row = grow0 + mi*16 + l4*4 + rr;
      if (row < E_EDGES) {
        size_t gi = (size_t)row*128 + col;
        outp[gi] = acc2[mi][rr] + edgep[gi];
      }
    }
}

// ---------------- stats: per-graph count, sum, sumsq of Y (batch sorted -> run accumulation) ----------------
__global__ void stats_kernel(const float* __restrict__ y, const int* __restrict__ batch,
                             float* __restrict__ gsum, float* __restrict__ gsum2,
                             float* __restrict__ gcnt) {
  const int col = threadIdx.x & 127;
  const int rp  = threadIdx.x >> 7;
  long r0 = (long)blockIdx.x * 1024;
  long rend = r0 + 1024; if (rend > E_EDGES) rend = E_EDGES;
  float s = 0.f, s2 = 0.f, sc = 0.f; int gcur = -1;
  for (long rr = r0 + rp; rr < rend; rr += 2) {
    int g = batch[rr];
    if (g != gcur) {
      if (gcur >= 0) {
        atomicAdd(&gsum[gcur*128+col], s); atomicAdd(&gsum2[gcur*128+col], s2);
        if (col == 0) atomicAdd(&gcnt[gcur], sc);
      }
      gcur = g; s = 0.f; s2 = 0.f; sc = 0.f;
    }
    float v = y[rr*128 + col];
    s += v; s2 += v*v; sc += 1.f;
  }
  if (gcur >= 0) {
    atomicAdd(&gsum[gcur*128+col], s); atomicAdd(&gsum2[gcur*128+col], s2);
    if (col == 0) atomicAdd(&gcnt[gcur], sc);
  }
}

// ---------------- finalize: scale/shift per (graph, dim) ----------------
__global__ void finalize_kernel(const float* __restrict__ gsum, const float* __restrict__ gsum2,
                                const float* __restrict__ cnt,
                                const float* __restrict__ gnw, const float* __restrict__ gnb,
                                const float* __restrict__ ms,
                                float* __restrict__ scale, float* __restrict__ shift) {
  int idx = blockIdx.x*blockDim.x + threadIdx.x;
  if (idx >= 64*128) return;
  int g = idx >> 7, d = idx & 127;
  float c = fmaxf(cnt[g], 1.0f);
  float mean = gsum[idx] / c;
  float mm = mean * ms[d];
  // E[(x-mm)^2] = E[x^2] - 2*mm*E[x] + mm^2
  float var = gsum2[idx] / c - 2.f*mm*mean + mm*mm;
  float sc = gnw[d] / sqrtf(var + EPSV);
  scale[idx] = sc;
  shift[idx] = gnb[d] - mm*sc;
}

// ---------------- norm: in-place y = y*scale[g] + shift[g] ----------------
__global__ void norm_kernel(float* __restrict__ y, const int* __restrict__ batch,
                            const float* __restrict__ scale, const float* __restrict__ shift) {
  long i = (long)blockIdx.x*blockDim.x + threadIdx.x;
  const long n4 = (long)E_EDGES * 32;
  long stride = (long)gridDim.x*blockDim.x;
  for (; i < n4; i += stride) {
    long row = i >> 5;
    int dq = (int)(i & 31) << 2;
    int g = batch[row];
    f32x4 v = *(f32x4*)(y + i*4);
    f32x4 sc = *(const f32x4*)(scale + g*128 + dq);
    f32x4 sh = *(const f32x4*)(shift + g*128 + dq);
    v = v*sc + sh;
    *(f32x4*)(y + i*4) = v;
  }
}

extern "C" void kernel_launch(void* const* d_in, const int* in_sizes, int n_in,
                              void* d_out, int out_size, void* d_ws, size_t ws_size,
                              hipStream_t stream) {
  const float* srcp  = (const float*)d_in[0];
  const float* destp = (const float*)d_in[1];
  const float* edgep = (const float*)d_in[2];
  const float* up    = (const float*)d_in[3];
  const int*   batch = (const int*)d_in[4];
  const float* W1    = (const float*)d_in[5];
  const float* b1    = (const float*)d_in[6];
  const float* W2    = (const float*)d_in[7];
  const float* b2    = (const float*)d_in[8];
  const float* gnw   = (const float*)d_in[9];
  const float* gnb   = (const float*)d_in[10];
  const float* ms    = (const float*)d_in[11];
  float* outp = (float*)d_out;

  char* ws = (char*)d_ws;
  u16*   w1f   = (u16*)(ws + 0);          // 458752 B
  u16*   w2f   = (u16*)(ws + 458752);     // 131072 B
  float* gsum  = (float*)(ws + 589824);   // 32768 B
  float* gsum2 = (float*)(ws + 622592);   // 32768 B
  float* cntp  = (float*)(ws + 655360);   // 1024 B
  float* scale = (float*)(ws + 656384);   // 32768 B
  float* shift = (float*)(ws + 689152);   // 32768 B

  hipMemsetAsync(ws + 589824, 0, 66560, stream);  // gsum, gsum2, cnt
  prep_weights<<<dim3(144), dim3(256), 0, stream>>>(W1, W2, w1f, w2f);

  fused_kernel<<<dim3(NBLK), dim3(512), 0, stream>>>(srcp, destp, edgep, up, batch,
                                                     b1, b2, w1f, w2f, outp);

  stats_kernel<<<dim3(489), dim3(256), 0, stream>>>(outp, batch, gsum, gsum2, cntp);
  finalize_kernel<<<dim3(32), dim3(256), 0, stream>>>(gsum, gsum2, cntp, gnw, gnb, ms, scale, shift);
  norm_kernel<<<dim3(2048), dim3(256), 0, stream>>>(outp, batch, scale, shift);
}

// Round 4
// 764.549 us; speedup vs baseline: 7.0726x; 1.1966x over previous
//
#include <hip/hip_runtime.h>
#include <stdint.h>

#define E_EDGES   500000
#define NBLK      7813        // ceil(E/64)
#define EPSV      1e-5f

typedef unsigned short u16;
typedef __attribute__((ext_vector_type(8))) short short8;
typedef __attribute__((ext_vector_type(4))) float f32x4;

__device__ __forceinline__ u16 f2bf(float f) {
  uint32_t u = __float_as_uint(f);
  u += 0x7fffu + ((u >> 16) & 1u);   // RNE
  return (u16)(u >> 16);
}

// ---------------- prep: weights -> bf16 B-fragment layout ----------------
// w1f[((n16*14 + k32)*64 + lane)*8 + j] = bf16(W1[k32*32+(lane>>4)*8+j][n16*16+(lane&15)])
// w2f[((n16*16 + k32)*64 + lane)*8 + j] = bf16(W2[k32*32+(lane>>4)*8+j][n16*16+(lane&15)])
__global__ void prep_weights(const float* __restrict__ W1, const float* __restrict__ W2,
                             u16* __restrict__ w1f, u16* __restrict__ w2f) {
  int idx = blockIdx.x * blockDim.x + threadIdx.x;
  if (idx < 32*14*64) {
    int lane = idx & 63; int t = idx >> 6; int k32 = t % 14; int n16 = t / 14;
    int n = n16*16 + (lane & 15); int k0 = k32*32 + (lane >> 4)*8;
    short8 pk;
#pragma unroll
    for (int j = 0; j < 8; ++j) pk[j] = (short)f2bf(W1[(size_t)(k0 + j)*512 + n]);
    *(short8*)&w1f[(size_t)idx * 8] = pk;
  } else if (idx < 32*14*64 + 8*16*64) {
    int i2 = idx - 32*14*64;
    int lane = i2 & 63; int t = i2 >> 6; int k32 = t % 16; int n16 = t / 16;
    int n = n16*16 + (lane & 15); int k0 = k32*32 + (lane >> 4)*8;
    short8 pk;
#pragma unroll
    for (int j = 0; j < 8; ++j) pk[j] = (short)f2bf(W2[(size_t)(k0 + j)*128 + n]);
    *(short8*)&w2f[(size_t)i2 * 8] = pk;
  }
}

// ---------------- fused: Y = relu(X@W1+b1)@W2 + b2 + edge ----------------
// Block: 64 edges. 8 waves; wave w owns hidden-cols [w*64, w*64+64) in GEMM1,
// out-cols [w*16, w*16+16) in GEMM2.
// LDS phases (union, 64 KB):  X [64][448] bf16 (56KB, stride 896B)
//                          -> H [64][512] bf16 (64KB, stride 1024B)
//                          -> Y [64][128] f32  (32KB, stride 512B)
// All phases XOR-swizzled: byte ^= (row&7)<<4 (verified uniform bank spread).
#define SWZ16(row, byte) ((byte) ^ (((row) & 7) << 4))

__global__ __launch_bounds__(512, 4)
void fused_kernel(const float* __restrict__ srcp, const float* __restrict__ destp,
                  const float* __restrict__ edgep, const float* __restrict__ up,
                  const int* __restrict__ batch, const float* __restrict__ b1,
                  const float* __restrict__ b2,
                  const u16* __restrict__ w1f, const u16* __restrict__ w2f,
                  float* __restrict__ outp) {
  const int tid  = threadIdx.x;
  const int lane = tid & 63;
  const int w    = tid >> 6;         // wave 0..7
  const int l15  = lane & 15, l4 = lane >> 4;

  __shared__ __align__(16) u16 lds[64*512];   // 64 KB
  char* ldsb = (char*)lds;

  const long grow0 = (long)blockIdx.x * 64;

  // ---- stage: entire X tile [64][448] f32 -> bf16 -> LDS (one barrier total)
  {
    const int srow = tid >> 3;          // 0..63
    const int c8   = (tid & 7) * 8;     // col octet within each 64-chunk
    const long sgrow = grow0 + srow;
    const bool inb = sgrow < E_EDGES;
    const long rb = inb ? sgrow : 0;
    const int  bat = batch[rb];
#pragma unroll
    for (int j = 0; j < 7; ++j) {
      const float* sp;
      if (j == 0)      sp = srcp  + rb*128 + c8;
      else if (j == 1) sp = srcp  + rb*128 + 64 + c8;
      else if (j == 2) sp = destp + rb*128 + c8;
      else if (j == 3) sp = destp + rb*128 + 64 + c8;
      else if (j == 4) sp = edgep + rb*128 + c8;
      else if (j == 5) sp = edgep + rb*128 + 64 + c8;
      else             sp = up + (size_t)bat*64 + c8;
      f32x4 t0 = *(const f32x4*)(sp);
      f32x4 t1 = *(const f32x4*)(sp + 4);
      short8 pk;
      pk[0]=(short)f2bf(t0[0]); pk[1]=(short)f2bf(t0[1]);
      pk[2]=(short)f2bf(t0[2]); pk[3]=(short)f2bf(t0[3]);
      pk[4]=(short)f2bf(t1[0]); pk[5]=(short)f2bf(t1[1]);
      pk[6]=(short)f2bf(t1[2]); pk[7]=(short)f2bf(t1[3]);
      if (!inb) { short8 z = {0,0,0,0,0,0,0,0}; pk = z; }
      *(short8*)(ldsb + srow*896 + SWZ16(srow, (j*64 + c8)*2)) = pk;
    }
  }
  __syncthreads();   // B1 — X fully staged

  // ---- GEMM1: 14 k32 iterations, barrier-free
  f32x4 acc1[4][4];
#pragma unroll
  for (int mi = 0; mi < 4; ++mi)
#pragma unroll
    for (int nj = 0; nj < 4; ++nj) {
      float bv = b1[w*64 + nj*16 + l15];
      acc1[mi][nj] = (f32x4){bv, bv, bv, bv};
    }

#pragma unroll 2
  for (int k32 = 0; k32 < 14; ++k32) {
    short8 a[4], b[4];
#pragma unroll
    for (int mi = 0; mi < 4; ++mi) {
      int row = mi*16 + l15;
      a[mi] = *(const short8*)(ldsb + row*896 + SWZ16(row, k32*64 + l4*16));
    }
#pragma unroll
    for (int nj = 0; nj < 4; ++nj) {
      int n16 = w*4 + nj;
      b[nj] = *(const short8*)&w1f[((size_t)(n16*14 + k32)*64 + lane)*8];
    }
#pragma unroll
    for (int mi = 0; mi < 4; ++mi)
#pragma unroll
      for (int nj = 0; nj < 4; ++nj)
        acc1[mi][nj] = __builtin_amdgcn_mfma_f32_16x16x32_bf16(a[mi], b[nj], acc1[mi][nj], 0, 0, 0);
  }
  __syncthreads();   // B2 — X reads done, LDS becomes H

  // ---- epilogue 1: relu -> bf16 -> H in LDS [64][512]
#pragma unroll
  for (int nj = 0; nj < 4; ++nj) {
    int n = w*64 + nj*16 + l15;
#pragma unroll
    for (int mi = 0; mi < 4; ++mi)
#pragma unroll
      for (int rr = 0; rr < 4; ++rr) {
        int row = mi*16 + l4*4 + rr;
        *(u16*)(ldsb + row*1024 + SWZ16(row, n*2)) = f2bf(fmaxf(acc1[mi][nj][rr], 0.f));
      }
  }
  __syncthreads();   // B3 — H ready

  // ---- GEMM2: 16 kb iterations, barrier-free. Wave w owns out-cols [w*16, w*16+16).
  const int col = w*16 + l15;
  float bv2 = b2[col];
  f32x4 acc2[4];
#pragma unroll
  for (int mi = 0; mi < 4; ++mi) acc2[mi] = (f32x4){bv2, bv2, bv2, bv2};

#pragma unroll 4
  for (int kb = 0; kb < 16; ++kb) {
    short8 bfrag = *(const short8*)&w2f[((size_t)(w*16 + kb)*64 + lane)*8];
#pragma unroll
    for (int mi = 0; mi < 4; ++mi) {
      int row = mi*16 + l15;
      short8 a = *(const short8*)(ldsb + row*1024 + SWZ16(row, kb*64 + l4*16));
      acc2[mi] = __builtin_amdgcn_mfma_f32_16x16x32_bf16(a, bfrag, acc2[mi], 0, 0, 0);
    }
  }
  __syncthreads();   // B4 — H reads done, LDS becomes Y (f32, 32 KB)

  // ---- bounce Y through LDS for coalesced store
#pragma unroll
  for (int mi = 0; mi < 4; ++mi)
#pragma unroll
    for (int rr = 0; rr < 4; ++rr) {
      int row = mi*16 + l4*4 + rr;
      *(float*)(ldsb + row*512 + SWZ16(row, col*4)) = acc2[mi][rr];
    }
  __syncthreads();   // B5 — Y ready

  {
    const int row = tid >> 3;
    const long grow = grow0 + row;
    if (grow < E_EDGES) {
      const int cb = (tid & 7) * 16;   // col base (floats)
      const float* ep = edgep + grow*128 + cb;
      float*       op = outp  + grow*128 + cb;
#pragma unroll
      for (int q = 0; q < 4; ++q) {
        f32x4 y = *(const f32x4*)(ldsb + row*512 + SWZ16(row, (cb + q*4)*4));
        f32x4 e = *(const f32x4*)(ep + q*4);
        y = y + e;
        *(f32x4*)(op + q*4) = y;
      }
    }
  }
}

// ---------------- stats: per-graph count, sum, sumsq of Y (batch sorted -> run accumulation) ----------------
__global__ void stats_kernel(const float* __restrict__ y, const int* __restrict__ batch,
                             float* __restrict__ gsum, float* __restrict__ gsum2,
                             float* __restrict__ gcnt) {
  const int col = threadIdx.x & 127;
  const int rp  = threadIdx.x >> 7;
  long r0 = (long)blockIdx.x * 512;
  long rend = r0 + 512; if (rend > E_EDGES) rend = E_EDGES;
  float s = 0.f, s2 = 0.f, sc = 0.f; int gcur = -1;
  for (long rr = r0 + rp; rr < rend; rr += 2) {
    int g = batch[rr];
    if (g != gcur) {
      if (gcur >= 0) {
        atomicAdd(&gsum[gcur*128+col], s); atomicAdd(&gsum2[gcur*128+col], s2);
        if (col == 0) atomicAdd(&gcnt[gcur], sc);
      }
      gcur = g; s = 0.f; s2 = 0.f; sc = 0.f;
    }
    float v = y[rr*128 + col];
    s += v; s2 += v*v; sc += 1.f;
  }
  if (gcur >= 0) {
    atomicAdd(&gsum[gcur*128+col], s); atomicAdd(&gsum2[gcur*128+col], s2);
    if (col == 0) atomicAdd(&gcnt[gcur], sc);
  }
}

// ---------------- finalize: scale/shift per (graph, dim) ----------------
__global__ void finalize_kernel(const float* __restrict__ gsum, const float* __restrict__ gsum2,
                                const float* __restrict__ cnt,
                                const float* __restrict__ gnw, const float* __restrict__ gnb,
                                const float* __restrict__ ms,
                                float* __restrict__ scale, float* __restrict__ shift) {
  int idx = blockIdx.x*blockDim.x + threadIdx.x;
  if (idx >= 64*128) return;
  int g = idx >> 7, d = idx & 127;
  float c = fmaxf(cnt[g], 1.0f);
  float mean = gsum[idx] / c;
  float mm = mean * ms[d];
  // E[(x-mm)^2] = E[x^2] - 2*mm*E[x] + mm^2
  float var = gsum2[idx] / c - 2.f*mm*mean + mm*mm;
  float sc = gnw[d] / sqrtf(var + EPSV);
  scale[idx] = sc;
  shift[idx] = gnb[d] - mm*sc;
}

// ---------------- norm: in-place y = y*scale[g] + shift[g] ----------------
__global__ void norm_kernel(float* __restrict__ y, const int* __restrict__ batch,
                            const float* __restrict__ scale, const float* __restrict__ shift) {
  long i = (long)blockIdx.x*blockDim.x + threadIdx.x;
  const long n4 = (long)E_EDGES * 32;
  long stride = (long)gridDim.x*blockDim.x;
  for (; i < n4; i += stride) {
    long row = i >> 5;
    int dq = (int)(i & 31) << 2;
    int g = batch[row];
    f32x4 v = *(f32x4*)(y + i*4);
    f32x4 sc = *(const f32x4*)(scale + g*128 + dq);
    f32x4 sh = *(const f32x4*)(shift + g*128 + dq);
    v = v*sc + sh;
    *(f32x4*)(y + i*4) = v;
  }
}

extern "C" void kernel_launch(void* const* d_in, const int* in_sizes, int n_in,
                              void* d_out, int out_size, void* d_ws, size_t ws_size,
                              hipStream_t stream) {
  const float* srcp  = (const float*)d_in[0];
  const float* destp = (const float*)d_in[1];
  const float* edgep = (const float*)d_in[2];
  const float* up    = (const float*)d_in[3];
  const int*   batch = (const int*)d_in[4];
  const float* W1    = (const float*)d_in[5];
  const float* b1    = (const float*)d_in[6];
  const float* W2    = (const float*)d_in[7];
  const float* b2    = (const float*)d_in[8];
  const float* gnw   = (const float*)d_in[9];
  const float* gnb   = (const float*)d_in[10];
  const float* ms    = (const float*)d_in[11];
  float* outp = (float*)d_out;

  char* ws = (char*)d_ws;
  u16*   w1f   = (u16*)(ws + 0);          // 458752 B
  u16*   w2f   = (u16*)(ws + 458752);     // 131072 B
  float* gsum  = (float*)(ws + 589824);   // 32768 B
  float* gsum2 = (float*)(ws + 622592);   // 32768 B
  float* cntp  = (float*)(ws + 655360);   // 1024 B
  float* scale = (float*)(ws + 656384);   // 32768 B
  float* shift = (float*)(ws + 689152);   // 32768 B

  hipMemsetAsync(ws + 589824, 0, 66560, stream);  // gsum, gsum2, cnt
  prep_weights<<<dim3(144), dim3(256), 0, stream>>>(W1, W2, w1f, w2f);

  fused_kernel<<<dim3(NBLK), dim3(512), 0, stream>>>(srcp, destp, edgep, up, batch,
                                                     b1, b2, w1f, w2f, outp);

  stats_kernel<<<dim3(977), dim3(256), 0, stream>>>(outp, batch, gsum, gsum2, cntp);
  finalize_kernel<<<dim3(32), dim3(256), 0, stream>>>(gsum, gsum2, cntp, gnw, gnb, ms, scale, shift);
  norm_kernel<<<dim3(2048), dim3(256), 0, stream>>>(outp, batch, scale, shift);
}

// Round 6
// 577.414 us; speedup vs baseline: 9.3647x; 1.3241x over previous
//
#include <hip/hip_runtime.h>
#include <stdint.h>

#define E_EDGES   500000
#define MBLK      32
#define NBLK      15625       // E / 32 exactly
#define EPSV      1e-5f

typedef unsigned short u16;
typedef __attribute__((ext_vector_type(8))) short short8;
typedef __attribute__((ext_vector_type(4))) float f32x4;

__device__ __forceinline__ u16 f2bf(float f) {
  uint32_t u = __float_as_uint(f);
  u += 0x7fffu + ((u >> 16) & 1u);   // RNE
  return (u16)(u >> 16);
}

// ---------------- prep: weights -> bf16 B-fragment layout ----------------
__global__ void prep_weights(const float* __restrict__ W1, const float* __restrict__ W2,
                             u16* __restrict__ w1f, u16* __restrict__ w2f) {
  int idx = blockIdx.x * blockDim.x + threadIdx.x;
  if (idx < 32*14*64) {
    int lane = idx & 63; int t = idx >> 6; int k32 = t % 14; int n16 = t / 14;
    int n = n16*16 + (lane & 15); int k0 = k32*32 + (lane >> 4)*8;
    short8 pk;
#pragma unroll
    for (int j = 0; j < 8; ++j) pk[j] = (short)f2bf(W1[(size_t)(k0 + j)*512 + n]);
    *(short8*)&w1f[(size_t)idx * 8] = pk;
  } else if (idx < 32*14*64 + 8*16*64) {
    int i2 = idx - 32*14*64;
    int lane = i2 & 63; int t = i2 >> 6; int k32 = t % 16; int n16 = t / 16;
    int n = n16*16 + (lane & 15); int k0 = k32*32 + (lane >> 4)*8;
    short8 pk;
#pragma unroll
    for (int j = 0; j < 8; ++j) pk[j] = (short)f2bf(W2[(size_t)(k0 + j)*128 + n]);
    *(short8*)&w2f[(size_t)i2 * 8] = pk;
  }
}

// ---------------- fused: Y = relu(X@W1+b1)@W2 + b2 + edge, + per-graph stats ----------------
// Block: 32 edges, 4 waves (256 thr). Wave w: hidden-cols [w*128,(w+1)*128) in GEMM1,
// out-cols [w*32,(w+1)*32) in GEMM2.
// LDS (32 KB union): X [32][448] bf16 (28K, stride 896) -> H [32][512] bf16 (32K, stride 1024)
//                 -> Y [32][128] f32 (16K, stride 512) + stat partials at [16K..24K) (linear slots).
#define SWZ16(row, byte) ((byte) ^ (((row) & 7) << 4))

__global__ __launch_bounds__(256, 4)
void fused_kernel(const float* __restrict__ srcp, const float* __restrict__ destp,
                  const float* __restrict__ edgep, const float* __restrict__ up,
                  const int* __restrict__ batch, const float* __restrict__ b1,
                  const float* __restrict__ b2,
                  const u16* __restrict__ w1f, const u16* __restrict__ w2f,
                  float* __restrict__ outp,
                  float* __restrict__ sums0, float* __restrict__ sums2,
                  float* __restrict__ cntsh, int nshard) {
  const int tid  = threadIdx.x;
  const int lane = tid & 63;
  const int w    = tid >> 6;         // wave 0..3
  const int l15  = lane & 15, l4 = lane >> 4;

  __shared__ __align__(16) u16 lds[32*512];   // 32 KB
  char* ldsb = (char*)lds;

  const long grow0 = (long)blockIdx.x * MBLK;

  // ---- stage: X tile [32][448] f32 -> bf16 -> LDS (one barrier)
  {
    const int srow = tid >> 3;          // 0..31
    const int c8   = (tid & 7) * 8;
    const long sgrow = grow0 + srow;
    const int  bat = batch[sgrow];
#pragma unroll
    for (int j = 0; j < 7; ++j) {
      const float* sp;
      if (j == 0)      sp = srcp  + sgrow*128 + c8;
      else if (j == 1) sp = srcp  + sgrow*128 + 64 + c8;
      else if (j == 2) sp = destp + sgrow*128 + c8;
      else if (j == 3) sp = destp + sgrow*128 + 64 + c8;
      else if (j == 4) sp = edgep + sgrow*128 + c8;
      else if (j == 5) sp = edgep + sgrow*128 + 64 + c8;
      else             sp = up + (size_t)bat*64 + c8;
      f32x4 t0 = *(const f32x4*)(sp);
      f32x4 t1 = *(const f32x4*)(sp + 4);
      short8 pk;
      pk[0]=(short)f2bf(t0[0]); pk[1]=(short)f2bf(t0[1]);
      pk[2]=(short)f2bf(t0[2]); pk[3]=(short)f2bf(t0[3]);
      pk[4]=(short)f2bf(t1[0]); pk[5]=(short)f2bf(t1[1]);
      pk[6]=(short)f2bf(t1[2]); pk[7]=(short)f2bf(t1[3]);
      *(short8*)(ldsb + srow*896 + SWZ16(srow, (j*64 + c8)*2)) = pk;
    }
  }
  __syncthreads();   // B1 — X staged

  // ---- GEMM1: 14 k32 iterations, barrier-free. acc1[2 rows16][8 cols16].
  f32x4 acc1[2][8];
#pragma unroll
  for (int mi = 0; mi < 2; ++mi)
#pragma unroll
    for (int nj = 0; nj < 8; ++nj) {
      float bv = b1[w*128 + nj*16 + l15];
      acc1[mi][nj] = (f32x4){bv, bv, bv, bv};
    }

#pragma unroll 2
  for (int k32 = 0; k32 < 14; ++k32) {
    short8 a[2], b[8];
#pragma unroll
    for (int mi = 0; mi < 2; ++mi) {
      int row = mi*16 + l15;
      a[mi] = *(const short8*)(ldsb + row*896 + SWZ16(row, k32*64 + l4*16));
    }
#pragma unroll
    for (int nj = 0; nj < 8; ++nj) {
      int n16 = w*8 + nj;
      b[nj] = *(const short8*)&w1f[((size_t)(n16*14 + k32)*64 + lane)*8];
    }
#pragma unroll
    for (int mi = 0; mi < 2; ++mi)
#pragma unroll
      for (int nj = 0; nj < 8; ++nj)
        acc1[mi][nj] = __builtin_amdgcn_mfma_f32_16x16x32_bf16(a[mi], b[nj], acc1[mi][nj], 0, 0, 0);
  }
  __syncthreads();   // B2 — X reads done, LDS becomes H

  // ---- epilogue 1: relu -> bf16 -> H [32][512]
#pragma unroll
  for (int nj = 0; nj < 8; ++nj) {
    int n = w*128 + nj*16 + l15;
#pragma unroll
    for (int mi = 0; mi < 2; ++mi)
#pragma unroll
      for (int rr = 0; rr < 4; ++rr) {
        int row = mi*16 + l4*4 + rr;
        *(u16*)(ldsb + row*1024 + SWZ16(row, n*2)) = f2bf(fmaxf(acc1[mi][nj][rr], 0.f));
      }
  }
  __syncthreads();   // B3 — H ready

  // ---- edge prefetch (drains at B4 after GEMM2's compute -> latency hidden)
  const int c4    = tid & 31;      // 16B col-quad
  const int rbase = tid >> 5;      // 0..7
  f32x4 ebuf[4];
#pragma unroll
  for (int p = 0; p < 4; ++p)
    ebuf[p] = *(const f32x4*)(edgep + (grow0 + rbase + p*8)*128 + c4*4);

  // ---- GEMM2: wave w owns out-cols [w*32, w*32+32). acc2[2][2].
  f32x4 acc2[2][2];
#pragma unroll
  for (int nj = 0; nj < 2; ++nj) {
    float bv = b2[w*32 + nj*16 + l15];
    acc2[0][nj] = (f32x4){bv, bv, bv, bv};
    acc2[1][nj] = (f32x4){bv, bv, bv, bv};
  }

#pragma unroll 4
  for (int kb = 0; kb < 16; ++kb) {
    short8 a2[2], bf[2];
#pragma unroll
    for (int mi = 0; mi < 2; ++mi) {
      int row = mi*16 + l15;
      a2[mi] = *(const short8*)(ldsb + row*1024 + SWZ16(row, kb*64 + l4*16));
    }
#pragma unroll
    for (int nj = 0; nj < 2; ++nj) {
      int n16 = w*2 + nj;
      bf[nj] = *(const short8*)&w2f[(((size_t)(n16*16 + kb))*64 + lane)*8];
    }
#pragma unroll
    for (int mi = 0; mi < 2; ++mi)
#pragma unroll
      for (int nj = 0; nj < 2; ++nj)
        acc2[mi][nj] = __builtin_amdgcn_mfma_f32_16x16x32_bf16(a2[mi], bf[nj], acc2[mi][nj], 0, 0, 0);
  }
  __syncthreads();   // B4 — H reads done, LDS becomes Y f32 [32][128]

  // ---- bounce Y through LDS (coalesced store + stats source)
#pragma unroll
  for (int mi = 0; mi < 2; ++mi)
#pragma unroll
    for (int nj = 0; nj < 2; ++nj) {
      int col = w*32 + nj*16 + l15;
#pragma unroll
      for (int rr = 0; rr < 4; ++rr) {
        int row = mi*16 + l4*4 + rr;
        *(float*)(ldsb + row*512 + SWZ16(row, col*4)) = acc2[mi][nj][rr];
      }
    }
  __syncthreads();   // B5 — Y ready

  // ---- store (+edge) and per-graph stats
  const int g0 = batch[grow0];
  const int g1 = batch[grow0 + MBLK - 1];
  const int sh = blockIdx.x & (nshard - 1);

  if (g0 == g1) {
    // fast path: single-graph block
    f32x4 s = (f32x4){0,0,0,0}, s2 = (f32x4){0,0,0,0};
#pragma unroll
    for (int p = 0; p < 4; ++p) {
      int row = rbase + p*8;
      f32x4 y = *(const f32x4*)(ldsb + row*512 + SWZ16(row, c4*16));
      y = y + ebuf[p];
      *(f32x4*)(outp + (grow0 + row)*128 + c4*4) = y;
      s = s + y; s2 = s2 + y*y;
    }
    // partials -> LDS [16K..24K): linear slot per (rbase,c4) — 32 B each, collision-free
    int slot = 16384 + (rbase*32 + c4)*32;
    *(f32x4*)(ldsb + slot)      = s;
    *(f32x4*)(ldsb + slot + 16) = s2;
    __syncthreads();   // B6
    // reduce 8 rbase slots: thread -> (c4r, stat, cq)
    int c4r = tid >> 3, stat = (tid >> 2) & 1, cq = tid & 3;
    float v = 0.f;
#pragma unroll
    for (int r = 0; r < 8; ++r)
      v += *(const float*)(ldsb + 16384 + (r*32 + c4r)*32 + stat*16 + cq*4);
    float* dst = stat ? sums2 : sums0;
    atomicAdd(&dst[(size_t)sh*8192 + g0*128 + c4r*4 + cq], v);
    if (tid == 0) atomicAdd(&cntsh[sh*64 + g0], (float)MBLK);
  } else {
    // slow path: graph boundary inside block (rare: ~63/15625)
    f32x4 s = (f32x4){0,0,0,0}, s2 = (f32x4){0,0,0,0};
    float rc = 0.f; int gcur = -1;
#pragma unroll
    for (int p = 0; p < 4; ++p) {
      int row = rbase + p*8;
      int g = batch[grow0 + row];
      if (g != gcur) {
        if (gcur >= 0) {
#pragma unroll
          for (int c = 0; c < 4; ++c) {
            atomicAdd(&sums0[(size_t)sh*8192 + gcur*128 + c4*4 + c], s[c]);
            atomicAdd(&sums2[(size_t)sh*8192 + gcur*128 + c4*4 + c], s2[c]);
          }
          if (c4 == 0) atomicAdd(&cntsh[sh*64 + gcur], rc);
        }
        gcur = g; s = (f32x4){0,0,0,0}; s2 = (f32x4){0,0,0,0}; rc = 0.f;
      }
      f32x4 y = *(const f32x4*)(ldsb + row*512 + SWZ16(row, c4*16));
      y = y + ebuf[p];
      *(f32x4*)(outp + (grow0 + row)*128 + c4*4) = y;
      s = s + y; s2 = s2 + y*y; rc += 1.f;
    }
#pragma unroll
    for (int c = 0; c < 4; ++c) {
      atomicAdd(&sums0[(size_t)sh*8192 + gcur*128 + c4*4 + c], s[c]);
      atomicAdd(&sums2[(size_t)sh*8192 + gcur*128 + c4*4 + c], s2[c]);
    }
    if (c4 == 0) atomicAdd(&cntsh[sh*64 + gcur], rc);
  }
}

// ---------------- finalize: combine shards -> scale/shift per (graph, dim) ----------------
__global__ void finalize_kernel(const float* __restrict__ sums0, const float* __restrict__ sums2,
                                const float* __restrict__ cntsh, int nshard,
                                const float* __restrict__ gnw, const float* __restrict__ gnb,
                                const float* __restrict__ ms,
                                float* __restrict__ scale, float* __restrict__ shift) {
  int idx = blockIdx.x*blockDim.x + threadIdx.x;
  if (idx >= 64*128) return;
  int g = idx >> 7, d = idx & 127;
  float s = 0.f, s2 = 0.f, c = 0.f;
  for (int sh = 0; sh < nshard; ++sh) {
    s  += sums0[(size_t)sh*8192 + idx];
    s2 += sums2[(size_t)sh*8192 + idx];
    c  += cntsh[sh*64 + g];
  }
  c = fmaxf(c, 1.0f);
  float mean = s / c;
  float mm = mean * ms[d];
  float var = fmaxf(s2 / c - 2.f*mm*mean + mm*mm, 0.f);
  float sc = gnw[d] / sqrtf(var + EPSV);
  scale[idx] = sc;
  shift[idx] = gnb[d] - mm*sc;
}

// ---------------- norm: in-place y = y*scale[g] + shift[g] ----------------
__global__ void norm_kernel(float* __restrict__ y, const int* __restrict__ batch,
                            const float* __restrict__ scale, const float* __restrict__ shift) {
  long i = (long)blockIdx.x*blockDim.x + threadIdx.x;
  const long n4 = (long)E_EDGES * 32;
  long stride = (long)gridDim.x*blockDim.x;
  for (; i < n4; i += stride) {
    long row = i >> 5;
    int dq = (int)(i & 31) << 2;
    int g = batch[row];
    f32x4 v = *(f32x4*)(y + i*4);
    f32x4 sc = *(const f32x4*)(scale + g*128 + dq);
    f32x4 sh = *(const f32x4*)(shift + g*128 + dq);
    v = v*sc + sh;
    *(f32x4*)(y + i*4) = v;
  }
}

extern "C" void kernel_launch(void* const* d_in, const int* in_sizes, int n_in,
                              void* d_out, int out_size, void* d_ws, size_t ws_size,
                              hipStream_t stream) {
  const float* srcp  = (const float*)d_in[0];
  const float* destp = (const float*)d_in[1];
  const float* edgep = (const float*)d_in[2];
  const float* up    = (const float*)d_in[3];
  const int*   batch = (const int*)d_in[4];
  const float* W1    = (const float*)d_in[5];
  const float* b1    = (const float*)d_in[6];
  const float* W2    = (const float*)d_in[7];
  const float* b2    = (const float*)d_in[8];
  const float* gnw   = (const float*)d_in[9];
  const float* gnb   = (const float*)d_in[10];
  const float* ms    = (const float*)d_in[11];
  float* outp = (float*)d_out;

  char* ws = (char*)d_ws;
  u16*   w1f   = (u16*)(ws + 0);          // 458752 B
  u16*   w2f   = (u16*)(ws + 458752);     // 131072 B -> 589824
  float* scale = (float*)(ws + 589824);   // 32768  -> 622592
  float* shift = (float*)(ws + 622592);   // 32768  -> 655360
  float* cntsh = (float*)(ws + 655360);   // 8192   -> 663552
  // shard sums: sums0 [nshard][8192] then sums2 [nshard][8192]
  int nshard = 32;
  while (nshard > 1 && 663552 + (size_t)nshard*65536 > ws_size) nshard >>= 1;
  float* sums0 = (float*)(ws + 663552);
  float* sums2 = (float*)(ws + 663552 + (size_t)nshard*32768);

  hipMemsetAsync(ws + 655360, 0, 8192 + (size_t)nshard*65536, stream);
  prep_weights<<<dim3(144), dim3(256), 0, stream>>>(W1, W2, w1f, w2f);

  fused_kernel<<<dim3(NBLK), dim3(256), 0, stream>>>(srcp, destp, edgep, up, batch,
                                                     b1, b2, w1f, w2f, outp,
                                                     sums0, sums2, cntsh, nshard);

  finalize_kernel<<<dim3(32), dim3(256), 0, stream>>>(sums0, sums2, cntsh, nshard,
                                                      gnw, gnb, ms, scale, shift);
  norm_kernel<<<dim3(2048), dim3(256), 0, stream>>>(outp, batch, scale, shift);
}